// Round 1
// baseline (46.104 us; speedup 1.0000x reference)
//
#include <hip/hip_runtime.h>
#include <cfloat>

#define B  32
#define C  3
#define H  512
#define W  512
#define HW (H * W)
#define CHW (C * H * W)
#define W4 (W / 4)

// v-channel: max over RGB of floor(clip(x,0,255)) == floor(clip(max over RGB))
__device__ __forceinline__ float vchan(float a, float b, float c) {
    float m = fmaxf(fmaxf(a, b), c);          // compiler fuses to v_max3_f32
    m = fminf(fmaxf(m, 0.0f), 255.0f);        // clamp -> v_med3_f32
    return floorf(m);
}

// Stage 1: per (b, h-chunk), per-column min/max of the V channel for pred & tgt.
// grid = B*HC blocks, 128 threads; lane t owns columns [4t, 4t+3].
__global__ __launch_bounds__(128) void s1_minmax(
        const float* __restrict__ pred, const float* __restrict__ tgt,
        float* __restrict__ ws, int HC, int rows) {
    const int b     = blockIdx.x / HC;
    const int chunk = blockIdx.x - b * HC;
    const int w4    = threadIdx.x;            // 0..127

    const float4* P = reinterpret_cast<const float4*>(pred) + (size_t)b * (CHW / 4);
    const float4* T = reinterpret_cast<const float4*>(tgt)  + (size_t)b * (CHW / 4);

    float4 mnP = make_float4( FLT_MAX,  FLT_MAX,  FLT_MAX,  FLT_MAX);
    float4 mxP = make_float4(-FLT_MAX, -FLT_MAX, -FLT_MAX, -FLT_MAX);
    float4 mnT = mnP;
    float4 mxT = mxP;

    const int h0 = chunk * rows;
    #pragma unroll 4
    for (int h = h0; h < h0 + rows; ++h) {
        const int base = h * W4 + w4;
        // prediction: 3 channels
        float4 a = P[base];
        float4 g = P[base +     (HW / 4)];
        float4 c2 = P[base + 2 * (HW / 4)];
        float v0 = vchan(a.x, g.x, c2.x);
        float v1 = vchan(a.y, g.y, c2.y);
        float v2 = vchan(a.z, g.z, c2.z);
        float v3 = vchan(a.w, g.w, c2.w);
        mnP.x = fminf(mnP.x, v0); mxP.x = fmaxf(mxP.x, v0);
        mnP.y = fminf(mnP.y, v1); mxP.y = fmaxf(mxP.y, v1);
        mnP.z = fminf(mnP.z, v2); mxP.z = fmaxf(mxP.z, v2);
        mnP.w = fminf(mnP.w, v3); mxP.w = fmaxf(mxP.w, v3);
        // target: 3 channels
        a  = T[base];
        g  = T[base +     (HW / 4)];
        c2 = T[base + 2 * (HW / 4)];
        v0 = vchan(a.x, g.x, c2.x);
        v1 = vchan(a.y, g.y, c2.y);
        v2 = vchan(a.z, g.z, c2.z);
        v3 = vchan(a.w, g.w, c2.w);
        mnT.x = fminf(mnT.x, v0); mxT.x = fmaxf(mxT.x, v0);
        mnT.y = fminf(mnT.y, v1); mxT.y = fmaxf(mxT.y, v1);
        mnT.z = fminf(mnT.z, v2); mxT.z = fmaxf(mxT.z, v2);
        mnT.w = fminf(mnT.w, v3); mxT.w = fmaxf(mxT.w, v3);
    }

    // ws layout: 4 arrays of [B][HC][W] floats: minP, maxP, minT, maxT
    const size_t arr = (size_t)B * HC * W4;   // in float4 units
    const size_t o   = ((size_t)b * HC + chunk) * W4 + w4;
    float4* wsv = reinterpret_cast<float4*>(ws);
    wsv[o]           = mnP;
    wsv[o + arr]     = mxP;
    wsv[o + 2 * arr] = mnT;
    wsv[o + 3 * arr] = mxT;
}

// Stage 2a: combine chunk partials per (b,w), squared diffs, block tree-reduce.
// grid = 64 blocks x 256 threads; pair i = blockIdx*256 + tid covers B*W = 16384.
__global__ __launch_bounds__(256) void s2a_reduce(
        const float* __restrict__ ws, double* __restrict__ partial, int HC) {
    const int i = blockIdx.x * 256 + threadIdx.x;   // 0..16383
    const int b = i / W;
    const int w = i - b * W;

    const size_t arr = (size_t)B * HC * W;
    const float* minP = ws;
    const float* maxP = ws + arr;
    const float* minT = ws + 2 * arr;
    const float* maxT = ws + 3 * arr;

    float mnP = FLT_MAX, mxP = -FLT_MAX, mnT = FLT_MAX, mxT = -FLT_MAX;
    for (int c = 0; c < HC; ++c) {
        const size_t o = ((size_t)b * HC + c) * W + w;
        mnP = fminf(mnP, minP[o]);
        mxP = fmaxf(mxP, maxP[o]);
        mnT = fminf(mnT, minT[o]);
        mxT = fmaxf(mxT, maxT[o]);
    }
    const float dmin = mnP - mnT;
    const float dmax = mxP - mxT;
    double s = (double)dmin * (double)dmin + (double)dmax * (double)dmax;

    __shared__ double sd[256];
    sd[threadIdx.x] = s;
    __syncthreads();
    for (int st = 128; st > 0; st >>= 1) {
        if (threadIdx.x < st) sd[threadIdx.x] += sd[threadIdx.x + st];
        __syncthreads();
    }
    if (threadIdx.x == 0) partial[blockIdx.x] = sd[0];
}

// Stage 2b: sum 64 partials, write mean-sum scalar.
__global__ __launch_bounds__(64) void s2b_final(
        const double* __restrict__ partial, float* __restrict__ out) {
    __shared__ double sd[64];
    sd[threadIdx.x] = partial[threadIdx.x];
    __syncthreads();
    for (int st = 32; st > 0; st >>= 1) {
        if (threadIdx.x < st) sd[threadIdx.x] += sd[threadIdx.x + st];
        __syncthreads();
    }
    if (threadIdx.x == 0) out[0] = (float)(sd[0] / (double)(B * W));
}

extern "C" void kernel_launch(void* const* d_in, const int* in_sizes, int n_in,
                              void* d_out, int out_size, void* d_ws, size_t ws_size,
                              hipStream_t stream) {
    const float* pred = (const float*)d_in[0];
    const float* tgt  = (const float*)d_in[1];
    float* out = (float*)d_out;
    float* wsf = (float*)d_ws;

    // Pick largest power-of-two chunk count whose partials fit in ws.
    int HC = 16;
    while (HC > 1 &&
           (size_t)4 * B * HC * W * sizeof(float) + 64 * sizeof(double) > ws_size) {
        HC >>= 1;
    }
    const int rows = H / HC;

    hipLaunchKernelGGL(s1_minmax, dim3(B * HC), dim3(128), 0, stream,
                       pred, tgt, wsf, HC, rows);

    double* partial = (double*)(wsf + (size_t)4 * B * HC * W);
    hipLaunchKernelGGL(s2a_reduce, dim3(64), dim3(256), 0, stream,
                       wsf, partial, HC);
    hipLaunchKernelGGL(s2b_final, dim3(1), dim3(64), 0, stream,
                       partial, out);
}